// Round 2
// baseline (8541.918 us; speedup 1.0000x reference)
//
#include <hip/hip_runtime.h>
#include <stdint.h>

#define SEQ 512
#define BAT 64
#define INF 256     // input features
#define HID 1024
#define SB  (SEQ*BAT)   // 32768 rows

typedef __attribute__((ext_vector_type(8))) short short8;
typedef __attribute__((ext_vector_type(4))) float f32x4;

union Frag8 { uint32_t u[4]; short8 s; };

// ---------- numeric helpers: fp32 <-> (bf16 hi, bf16 lo) ----------
__device__ __forceinline__ uint32_t bf16hi_rne(uint32_t u){
  return (u + 0x7FFFu + ((u >> 16) & 1u)) & 0xFFFF0000u;
}
__device__ __forceinline__ uint32_t pack_split(float v){
  uint32_t hi = bf16hi_rne(__float_as_uint(v));
  float r = v - __uint_as_float(hi);
  uint32_t lo = bf16hi_rne(__float_as_uint(r)) >> 16;
  return hi | lo;                              // (hi16<<16) | lo16
}
__device__ __forceinline__ void unpack_pair(uint32_t u0, uint32_t u1,
                                            uint32_t& h, uint32_t& l){
  h = __builtin_amdgcn_perm(u1, u0, 0x07060302u);  // {u0.b2,u0.b3,u1.b2,u1.b3}
  l = __builtin_amdgcn_perm(u1, u0, 0x05040100u);  // {u0.b0,u0.b1,u1.b0,u1.b1}
}
__device__ __forceinline__ void gl16(const void* g, void* l){
  __builtin_amdgcn_global_load_lds(
      (const __attribute__((address_space(1))) void*)g,
      (__attribute__((address_space(3))) void*)l, 16, 0, 0);
}

// ---------- prep kernels ----------
// Wcomb[g][i] = sum_h Wih0[g][h] * Win[h][i]; grid 64 blocks x 16 rows
__global__ __launch_bounds__(256) void wcomb_kernel(const float* __restrict__ A,
                                                    const float* __restrict__ B,
                                                    float* __restrict__ C){
  __shared__ float As[16][64];
  __shared__ float Bs[64][256];
  const int tid = threadIdx.x;
  const int g0 = blockIdx.x * 16;
  float acc[16];
#pragma unroll
  for (int g = 0; g < 16; ++g) acc[g] = 0.f;
  for (int h0 = 0; h0 < HID; h0 += 64){
    __syncthreads();
#pragma unroll
    for (int j = 0; j < 4; ++j){
      int c = j*256 + tid;
      As[c >> 6][c & 63] = A[(size_t)(g0 + (c >> 6))*HID + h0 + (c & 63)];
    }
#pragma unroll
    for (int j = 0; j < 64; ++j) Bs[j][tid] = B[(size_t)(h0 + j)*INF + tid];
    __syncthreads();
#pragma unroll
    for (int hh = 0; hh < 64; hh += 4){
      float b0 = Bs[hh][tid], b1 = Bs[hh+1][tid], b2 = Bs[hh+2][tid], b3 = Bs[hh+3][tid];
#pragma unroll
      for (int g = 0; g < 16; ++g){
        const float4 a = *(const float4*)&As[g][hh];
        acc[g] += a.x*b0 + a.y*b1 + a.z*b2 + a.w*b3;
      }
    }
  }
#pragma unroll
  for (int g = 0; g < 16; ++g) C[(size_t)(g0 + g)*INF + tid] = acc[g];
}

// bcomb[g] = bih0[g] + sum_h Wih0[g][h]*bin[h]; one block per g
__global__ __launch_bounds__(256) void bcomb_kernel(const float* __restrict__ Wih0,
                                                    const float* __restrict__ bin,
                                                    const float* __restrict__ bih0,
                                                    float* __restrict__ bcomb){
  __shared__ float r[4];
  const int g = blockIdx.x, tid = threadIdx.x;
  float s = 0.f;
  for (int h = tid; h < HID; h += 256) s += Wih0[(size_t)g*HID + h] * bin[h];
  for (int o = 32; o > 0; o >>= 1) s += __shfl_down(s, o, 64);
  if ((tid & 63) == 0) r[tid >> 6] = s;
  __syncthreads();
  if (tid == 0) bcomb[g] = bih0[g] + r[0] + r[1] + r[2] + r[3];
}

__global__ void split_w(const float* __restrict__ in, uint16_t* __restrict__ hi,
                        uint16_t* __restrict__ lo, int n){
  int i = blockIdx.x*256 + threadIdx.x;
  if (i < n){
    float v = in[i];
    uint32_t h = bf16hi_rne(__float_as_uint(v));
    float r = v - __uint_as_float(h);
    hi[i] = (uint16_t)(h >> 16);
    lo[i] = (uint16_t)(bf16hi_rne(__float_as_uint(r)) >> 16);
  }
}

__global__ void pack_x(const float* __restrict__ in, uint32_t* __restrict__ out, int n){
  int i = blockIdx.x*256 + threadIdx.x;
  if (i < n) out[i] = pack_split(in[i]);
}

// ---------- batched split GEMM: C[M][N] = unpack(A)[M][K] @ (Whi+Wlo)[N][K]^T + bias ----------
__global__ __launch_bounds__(256) void gemm_split(
    const uint32_t* __restrict__ A, const uint16_t* __restrict__ Whi,
    const uint16_t* __restrict__ Wlo, const float* __restrict__ bias,
    float* __restrict__ C, int N, int K)
{
  __shared__ uint32_t Al[128*32];   // 16 KB packed
  __shared__ uint16_t Wh[128*32];   // 8 KB
  __shared__ uint16_t Wl[128*32];   // 8 KB
  const int tid  = threadIdx.x;
  const int lane = tid & 63;
  const int w    = tid >> 6;
  const int wm   = w >> 1, wn = w & 1;
  const int lr   = lane & 15, kg = lane >> 4;
  const int bm   = blockIdx.x, bn = blockIdx.y;

  const uint32_t* Ag  = A   + (size_t)bm*128*K;
  const uint16_t* Whg = Whi + (size_t)bn*128*K;
  const uint16_t* Wlg = Wlo + (size_t)bn*128*K;

  f32x4 acc[4][4];
#pragma unroll
  for (int i = 0; i < 4; ++i)
#pragma unroll
    for (int j = 0; j < 4; ++j) acc[i][j] = (f32x4){0.f,0.f,0.f,0.f};

  for (int ks = 0; ks < K; ks += 32){
    __syncthreads();
#pragma unroll
    for (int j = 0; j < 4; ++j){
      int c = j*256 + tid;
      int row = c >> 3, kc = c & 7;
      int kcs = kc ^ ((row & 3) << 1);
      gl16(Ag + (size_t)row*K + ks + kcs*4, (char*)Al + c*16);
    }
#pragma unroll
    for (int j = 0; j < 2; ++j){
      int c = j*256 + tid;
      int row = c >> 2, kc = c & 3;
      int kcs = kc ^ (row & 3);
      gl16(Whg + (size_t)row*K + ks + kcs*8, (char*)Wh + c*16);
      gl16(Wlg + (size_t)row*K + ks + kcs*8, (char*)Wl + c*16);
    }
    __syncthreads();

    short8 ah[4], al[4];
#pragma unroll
    for (int mt = 0; mt < 4; ++mt){
      int row = wm*64 + mt*16 + lr;
      int c2  = kg ^ (row & 3);
      const uint32_t* p = &Al[row*32 + c2*8];
      uint4 a0 = *(const uint4*)p;
      uint4 a1 = *(const uint4*)(p + 4);
      Frag8 fh, fl;
      unpack_pair(a0.x, a0.y, fh.u[0], fl.u[0]);
      unpack_pair(a0.z, a0.w, fh.u[1], fl.u[1]);
      unpack_pair(a1.x, a1.y, fh.u[2], fl.u[2]);
      unpack_pair(a1.z, a1.w, fh.u[3], fl.u[3]);
      ah[mt] = fh.s; al[mt] = fl.s;
    }
#pragma unroll
    for (int nt = 0; nt < 4; ++nt){
      int row = wn*64 + nt*16 + lr;
      int kc  = kg ^ (row & 3);
      short8 whf = *(const short8*)&Wh[row*32 + kc*8];
      short8 wlf = *(const short8*)&Wl[row*32 + kc*8];
#pragma unroll
      for (int mt = 0; mt < 4; ++mt){
        acc[mt][nt] = __builtin_amdgcn_mfma_f32_16x16x32_bf16(ah[mt], whf, acc[mt][nt], 0,0,0);
        acc[mt][nt] = __builtin_amdgcn_mfma_f32_16x16x32_bf16(al[mt], whf, acc[mt][nt], 0,0,0);
        acc[mt][nt] = __builtin_amdgcn_mfma_f32_16x16x32_bf16(ah[mt], wlf, acc[mt][nt], 0,0,0);
      }
    }
  }
#pragma unroll
  for (int nt = 0; nt < 4; ++nt){
    int col = bn*128 + wn*64 + nt*16 + lr;
    float bv = bias[col];
#pragma unroll
    for (int mt = 0; mt < 4; ++mt){
#pragma unroll
      for (int r = 0; r < 4; ++r){
        int rowg = bm*128 + wm*64 + mt*16 + kg*4 + r;
        C[(size_t)rowg*N + col] = acc[mt][nt][r] + bv;
      }
    }
  }
}

// ---------- recurrent step: hout = tanh(pre + Whh*(hhi+hlo) + bhh), packed ----------
// grid 256: mt=bid>>6 (batch 16-row tile), nt=bid&63 (col 16-tile); 4 waves split K.
__global__ __launch_bounds__(256) void rnn_step(
    const float* pre, uint32_t* hout, const uint32_t* hprev, uint32_t* hstate,
    const uint16_t* __restrict__ Whi, const uint16_t* __restrict__ Wlo,
    const float* __restrict__ bhh)
{
  __shared__ float red[4*64*4];
  const int tid  = threadIdx.x;
  const int lane = tid & 63;
  const int w    = tid >> 6;
  const int lr   = lane & 15, kg = lane >> 4;
  const int mt   = blockIdx.x >> 6, nt = blockIdx.x & 63;

  f32x4 acc = (f32x4){0.f,0.f,0.f,0.f};
  if (hprev){
    const uint32_t* Ap  = hprev + (size_t)(mt*16 + lr)*HID + w*256 + kg*8;
    const uint16_t* Whp = Whi   + (size_t)(nt*16 + lr)*HID + w*256 + kg*8;
    const uint16_t* Wlp = Wlo   + (size_t)(nt*16 + lr)*HID + w*256 + kg*8;
#pragma unroll
    for (int ks = 0; ks < 8; ++ks){
      uint4 a0 = *(const uint4*)Ap;
      uint4 a1 = *(const uint4*)(Ap + 4);
      Frag8 fh, fl;
      unpack_pair(a0.x, a0.y, fh.u[0], fl.u[0]);
      unpack_pair(a0.z, a0.w, fh.u[1], fl.u[1]);
      unpack_pair(a1.x, a1.y, fh.u[2], fl.u[2]);
      unpack_pair(a1.z, a1.w, fh.u[3], fl.u[3]);
      short8 whf = *(const short8*)Whp;
      short8 wlf = *(const short8*)Wlp;
      acc = __builtin_amdgcn_mfma_f32_16x16x32_bf16(fh.s, whf, acc, 0,0,0);
      acc = __builtin_amdgcn_mfma_f32_16x16x32_bf16(fl.s, whf, acc, 0,0,0);
      acc = __builtin_amdgcn_mfma_f32_16x16x32_bf16(fh.s, wlf, acc, 0,0,0);
      Ap += 32; Whp += 32; Wlp += 32;
    }
  }
  *(f32x4*)&red[(w*64 + lane)*4] = acc;
  __syncthreads();
  if (w == 0){
    f32x4 s0 = *(const f32x4*)&red[lane*4];
    f32x4 s1 = *(const f32x4*)&red[(64 + lane)*4];
    f32x4 s2 = *(const f32x4*)&red[(128 + lane)*4];
    f32x4 s3 = *(const f32x4*)&red[(192 + lane)*4];
    f32x4 s = (s0 + s1) + (s2 + s3);
    const int col = nt*16 + lr;
    const float bv = bhh[col];
#pragma unroll
    for (int r = 0; r < 4; ++r){
      int row = mt*16 + kg*4 + r;
      size_t idx = (size_t)row*HID + col;
      float v = tanhf(s[r] + pre[idx] + bv);
      uint32_t p = pack_split(v);
      hout[idx] = p;
      if (hstate) hstate[idx] = p;
    }
  }
}

// ---------- hidden output from carried states ----------
__global__ void extract_hidden(const uint32_t* __restrict__ h0s,
                               const uint32_t* __restrict__ h1s,
                               float* __restrict__ out){
  int i = blockIdx.x*256 + threadIdx.x;   // 0..131071
  uint32_t p = (i >> 16) ? h1s[i & 65535] : h0s[i & 65535];
  out[(size_t)SB*INF + i] = __uint_as_float(p & 0xFFFF0000u) + __uint_as_float(p << 16);
}

// ---------- host ----------
extern "C" void kernel_launch(void* const* d_in, const int* in_sizes, int n_in,
                              void* d_out, int out_size, void* d_ws, size_t ws_size,
                              hipStream_t stream)
{
  const float* x    = (const float*)d_in[0];
  const float* W_in = (const float*)d_in[1];
  const float* b_in = (const float*)d_in[2];
  const float* W_ih = (const float*)d_in[3];   // [2][H][H]
  const float* W_hh = (const float*)d_in[4];   // [2][H][H]
  const float* b_ih = (const float*)d_in[5];   // [2][H]
  const float* b_hh = (const float*)d_in[6];   // [2][H]
  const float* W_out= (const float*)d_in[7];   // [I][H]
  const float* b_out= (const float*)d_in[8];
  float* out = (float*)d_out;
  (void)in_sizes; (void)n_in; (void)out_size;

  // ---- choose chunk length T to fit ws_size ----
  // fixed = 16,257,024 B; per-T = 589,824 B
  const size_t fixedB = 16257024;
  const size_t perT   = 589824;
  int T = 512;
  while (T > 2 && fixedB + (size_t)T*perT + 65536 > ws_size) T >>= 1;
  const int nchunk = SEQ / T;

  char* ws = (char*)d_ws;
  size_t off = 0;
  auto alloc = [&](size_t bytes)->void*{
    void* p = ws + off; off += (bytes + 255) & ~(size_t)255; return p;
  };
  float*    buf0   = (float*)   alloc((size_t)T*BAT*HID*4);  // pre0 -> packed h0 (chunk)
  float*    buf1   = (float*)   alloc((size_t)T*BAT*HID*4);  // pre1 -> packed h1 (chunk)
  uint32_t* xp     = (uint32_t*)alloc((size_t)T*BAT*INF*4);  // packed x (chunk)
  float*    WcombF = (float*)   alloc((size_t)HID*INF*4);
  uint16_t* Wc_hi  = (uint16_t*)alloc((size_t)HID*INF*2);
  uint16_t* Wc_lo  = (uint16_t*)alloc((size_t)HID*INF*2);
  uint16_t* Wih1_hi= (uint16_t*)alloc((size_t)HID*HID*2);
  uint16_t* Wih1_lo= (uint16_t*)alloc((size_t)HID*HID*2);
  uint16_t* Whh0_hi= (uint16_t*)alloc((size_t)HID*HID*2);
  uint16_t* Whh0_lo= (uint16_t*)alloc((size_t)HID*HID*2);
  uint16_t* Whh1_hi= (uint16_t*)alloc((size_t)HID*HID*2);
  uint16_t* Whh1_lo= (uint16_t*)alloc((size_t)HID*HID*2);
  uint16_t* Wout_hi= (uint16_t*)alloc((size_t)INF*HID*2);
  uint16_t* Wout_lo= (uint16_t*)alloc((size_t)INF*HID*2);
  float*    bcomb  = (float*)   alloc((size_t)HID*4);
  uint32_t* h0s    = (uint32_t*)alloc((size_t)BAT*HID*4);
  uint32_t* h1s    = (uint32_t*)alloc((size_t)BAT*HID*4);

  // ---- prep ----
  wcomb_kernel<<<HID/16, 256, 0, stream>>>(W_ih, W_in, WcombF);
  bcomb_kernel<<<HID, 256, 0, stream>>>(W_ih, b_in, b_ih, bcomb);
  split_w<<<(HID*INF+255)/256, 256, 0, stream>>>(WcombF, Wc_hi, Wc_lo, HID*INF);
  split_w<<<(HID*HID+255)/256, 256, 0, stream>>>(W_ih + (size_t)HID*HID, Wih1_hi, Wih1_lo, HID*HID);
  split_w<<<(HID*HID+255)/256, 256, 0, stream>>>(W_hh, Whh0_hi, Whh0_lo, HID*HID);
  split_w<<<(HID*HID+255)/256, 256, 0, stream>>>(W_hh + (size_t)HID*HID, Whh1_hi, Whh1_lo, HID*HID);
  split_w<<<(INF*HID+255)/256, 256, 0, stream>>>(W_out, Wout_hi, Wout_lo, INF*HID);

  // ---- chunked pipeline ----
  for (int c = 0; c < nchunk; ++c){
    const float* xc = x + (size_t)c*T*BAT*INF;
    pack_x<<<T*BAT*INF/256, 256, 0, stream>>>(xc, xp, T*BAT*INF);
    // pre0 chunk = xp @ Wcomb^T + bcomb
    gemm_split<<<dim3(T*64/128, HID/128), 256, 0, stream>>>(xp, Wc_hi, Wc_lo, bcomb, buf0, HID, INF);
    // layer0 scan over chunk (in place)
    for (int tc = 0; tc < T; ++tc){
      float* pre = buf0 + (size_t)tc*BAT*HID;
      const uint32_t* hp = (tc == 0)
          ? (c == 0 ? (const uint32_t*)nullptr : (const uint32_t*)h0s)
          : (const uint32_t*)(buf0 + (size_t)(tc-1)*BAT*HID);
      rnn_step<<<256, 256, 0, stream>>>(pre, (uint32_t*)pre, hp,
                                        (tc == T-1) ? h0s : nullptr,
                                        Whh0_hi, Whh0_lo, b_hh);
    }
    // pre1 chunk = h0chunk @ Wih1^T + b_ih1
    gemm_split<<<dim3(T*64/128, HID/128), 256, 0, stream>>>((const uint32_t*)buf0, Wih1_hi, Wih1_lo,
                                                            b_ih + HID, buf1, HID, HID);
    // layer1 scan over chunk
    for (int tc = 0; tc < T; ++tc){
      float* pre = buf1 + (size_t)tc*BAT*HID;
      const uint32_t* hp = (tc == 0)
          ? (c == 0 ? (const uint32_t*)nullptr : (const uint32_t*)h1s)
          : (const uint32_t*)(buf1 + (size_t)(tc-1)*BAT*HID);
      rnn_step<<<256, 256, 0, stream>>>(pre, (uint32_t*)pre, hp,
                                        (tc == T-1) ? h1s : nullptr,
                                        Whh1_hi, Whh1_lo, b_hh + HID);
    }
    // out chunk = h1chunk @ Wout^T + b_out
    gemm_split<<<dim3(T*64/128, INF/128), 256, 0, stream>>>((const uint32_t*)buf1, Wout_hi, Wout_lo,
                                                            b_out, out + (size_t)c*T*BAT*INF, INF, HID);
  }
  extract_hidden<<<(2*BAT*HID)/256, 256, 0, stream>>>(h0s, h1s, out);
}

// Round 3
// 6780.600 us; speedup vs baseline: 1.2598x; 1.2598x over previous
//
#include <hip/hip_runtime.h>
#include <stdint.h>

#define SEQ 512
#define BAT 64
#define INF 256     // input features
#define HID 1024
#define SB  (SEQ*BAT)   // 32768 rows
#define NWG_PERSIST 96

typedef __attribute__((ext_vector_type(8))) short short8;
typedef __attribute__((ext_vector_type(4))) float f32x4;

union Frag8 { uint32_t u[4]; short8 s; };

// ---------- numeric helpers: fp32 <-> (bf16 hi, bf16 lo) ----------
__device__ __forceinline__ uint32_t bf16hi_rne(uint32_t u){
  return (u + 0x7FFFu + ((u >> 16) & 1u)) & 0xFFFF0000u;
}
__device__ __forceinline__ uint32_t pack_split(float v){
  uint32_t hi = bf16hi_rne(__float_as_uint(v));
  float r = v - __uint_as_float(hi);
  uint32_t lo = bf16hi_rne(__float_as_uint(r)) >> 16;
  return hi | lo;                              // (hi16<<16) | lo16
}
__device__ __forceinline__ void unpack_pair(uint32_t u0, uint32_t u1,
                                            uint32_t& h, uint32_t& l){
  h = __builtin_amdgcn_perm(u1, u0, 0x07060302u);  // {u0.b2,u0.b3,u1.b2,u1.b3}
  l = __builtin_amdgcn_perm(u1, u0, 0x05040100u);  // {u0.b0,u0.b1,u1.b0,u1.b1}
}
__device__ __forceinline__ void gl16(const void* g, void* l){
  __builtin_amdgcn_global_load_lds(
      (const __attribute__((address_space(1))) void*)g,
      (__attribute__((address_space(3))) void*)l, 16, 0, 0);
}

// ---------- prep kernels ----------
__global__ __launch_bounds__(256) void wcomb_kernel(const float* __restrict__ A,
                                                    const float* __restrict__ B,
                                                    float* __restrict__ C){
  __shared__ float As[16][64];
  __shared__ float Bs[64][256];
  const int tid = threadIdx.x;
  const int g0 = blockIdx.x * 16;
  float acc[16];
#pragma unroll
  for (int g = 0; g < 16; ++g) acc[g] = 0.f;
  for (int h0 = 0; h0 < HID; h0 += 64){
    __syncthreads();
#pragma unroll
    for (int j = 0; j < 4; ++j){
      int c = j*256 + tid;
      As[c >> 6][c & 63] = A[(size_t)(g0 + (c >> 6))*HID + h0 + (c & 63)];
    }
#pragma unroll
    for (int j = 0; j < 64; ++j) Bs[j][tid] = B[(size_t)(h0 + j)*INF + tid];
    __syncthreads();
#pragma unroll
    for (int hh = 0; hh < 64; hh += 4){
      float b0 = Bs[hh][tid], b1 = Bs[hh+1][tid], b2 = Bs[hh+2][tid], b3 = Bs[hh+3][tid];
#pragma unroll
      for (int g = 0; g < 16; ++g){
        const float4 a = *(const float4*)&As[g][hh];
        acc[g] += a.x*b0 + a.y*b1 + a.z*b2 + a.w*b3;
      }
    }
  }
#pragma unroll
  for (int g = 0; g < 16; ++g) C[(size_t)(g0 + g)*INF + tid] = acc[g];
}

__global__ __launch_bounds__(256) void bcomb_kernel(const float* __restrict__ Wih0,
                                                    const float* __restrict__ bin,
                                                    const float* __restrict__ bih0,
                                                    float* __restrict__ bcomb){
  __shared__ float r[4];
  const int g = blockIdx.x, tid = threadIdx.x;
  float s = 0.f;
  for (int h = tid; h < HID; h += 256) s += Wih0[(size_t)g*HID + h] * bin[h];
  for (int o = 32; o > 0; o >>= 1) s += __shfl_down(s, o, 64);
  if ((tid & 63) == 0) r[tid >> 6] = s;
  __syncthreads();
  if (tid == 0) bcomb[g] = bih0[g] + r[0] + r[1] + r[2] + r[3];
}

__global__ void split_w(const float* __restrict__ in, uint16_t* __restrict__ hi,
                        uint16_t* __restrict__ lo, int n){
  int i = blockIdx.x*256 + threadIdx.x;
  if (i < n){
    float v = in[i];
    uint32_t h = bf16hi_rne(__float_as_uint(v));
    float r = v - __uint_as_float(h);
    hi[i] = (uint16_t)(h >> 16);
    lo[i] = (uint16_t)(bf16hi_rne(__float_as_uint(r)) >> 16);
  }
}

__global__ void pack_x(const float* __restrict__ in, uint32_t* __restrict__ out, int n){
  int i = blockIdx.x*256 + threadIdx.x;
  if (i < n) out[i] = pack_split(in[i]);
}

// ---------- batched split GEMM: C[M][N] = unpack(A)[M][K] @ (Whi+Wlo)[N][K]^T + bias ----------
__global__ __launch_bounds__(256) void gemm_split(
    const uint32_t* __restrict__ A, const uint16_t* __restrict__ Whi,
    const uint16_t* __restrict__ Wlo, const float* __restrict__ bias,
    float* __restrict__ C, int N, int K)
{
  __shared__ uint32_t Al[128*32];
  __shared__ uint16_t Wh[128*32];
  __shared__ uint16_t Wl[128*32];
  const int tid  = threadIdx.x;
  const int lane = tid & 63;
  const int w    = tid >> 6;
  const int wm   = w >> 1, wn = w & 1;
  const int lr   = lane & 15, kg = lane >> 4;
  const int bm   = blockIdx.x, bn = blockIdx.y;

  const uint32_t* Ag  = A   + (size_t)bm*128*K;
  const uint16_t* Whg = Whi + (size_t)bn*128*K;
  const uint16_t* Wlg = Wlo + (size_t)bn*128*K;

  f32x4 acc[4][4];
#pragma unroll
  for (int i = 0; i < 4; ++i)
#pragma unroll
    for (int j = 0; j < 4; ++j) acc[i][j] = (f32x4){0.f,0.f,0.f,0.f};

  for (int ks = 0; ks < K; ks += 32){
    __syncthreads();
#pragma unroll
    for (int j = 0; j < 4; ++j){
      int c = j*256 + tid;
      int row = c >> 3, kc = c & 7;
      int kcs = kc ^ ((row & 3) << 1);
      gl16(Ag + (size_t)row*K + ks + kcs*4, (char*)Al + c*16);
    }
#pragma unroll
    for (int j = 0; j < 2; ++j){
      int c = j*256 + tid;
      int row = c >> 2, kc = c & 3;
      int kcs = kc ^ (row & 3);
      gl16(Whg + (size_t)row*K + ks + kcs*8, (char*)Wh + c*16);
      gl16(Wlg + (size_t)row*K + ks + kcs*8, (char*)Wl + c*16);
    }
    __syncthreads();

    short8 ah[4], al[4];
#pragma unroll
    for (int mt = 0; mt < 4; ++mt){
      int row = wm*64 + mt*16 + lr;
      int c2  = kg ^ (row & 3);
      const uint32_t* p = &Al[row*32 + c2*8];
      uint4 a0 = *(const uint4*)p;
      uint4 a1 = *(const uint4*)(p + 4);
      Frag8 fh, fl;
      unpack_pair(a0.x, a0.y, fh.u[0], fl.u[0]);
      unpack_pair(a0.z, a0.w, fh.u[1], fl.u[1]);
      unpack_pair(a1.x, a1.y, fh.u[2], fl.u[2]);
      unpack_pair(a1.z, a1.w, fh.u[3], fl.u[3]);
      ah[mt] = fh.s; al[mt] = fl.s;
    }
#pragma unroll
    for (int nt = 0; nt < 4; ++nt){
      int row = wn*64 + nt*16 + lr;
      int kc  = kg ^ (row & 3);
      short8 whf = *(const short8*)&Wh[row*32 + kc*8];
      short8 wlf = *(const short8*)&Wl[row*32 + kc*8];
#pragma unroll
      for (int mt = 0; mt < 4; ++mt){
        acc[mt][nt] = __builtin_amdgcn_mfma_f32_16x16x32_bf16(ah[mt], whf, acc[mt][nt], 0,0,0);
        acc[mt][nt] = __builtin_amdgcn_mfma_f32_16x16x32_bf16(al[mt], whf, acc[mt][nt], 0,0,0);
        acc[mt][nt] = __builtin_amdgcn_mfma_f32_16x16x32_bf16(ah[mt], wlf, acc[mt][nt], 0,0,0);
      }
    }
  }
#pragma unroll
  for (int nt = 0; nt < 4; ++nt){
    int col = bn*128 + wn*64 + nt*16 + lr;
    float bv = bias[col];
#pragma unroll
    for (int mt = 0; mt < 4; ++mt){
#pragma unroll
      for (int r = 0; r < 4; ++r){
        int rowg = bm*128 + wm*64 + mt*16 + kg*4 + r;
        C[(size_t)rowg*N + col] = acc[mt][nt][r] + bv;
      }
    }
  }
}

// ---------- persistent wavefront scan kernel ----------
// 96 WGs x 512 thr. group = wg>>5: 0 = L0 recurrence (t=r), 1 = Wih1*h0 (t=r-1),
// 2 = L1 recurrence (t=r-2). Each WG: rows [wgRow*32,+32), cols [wgN*64,+64).
// 8 waves K-split (128 each); weights held in VGPRs (hi+lo bf16); LDS reduce.
__global__ __launch_bounds__(512, 2) void rnn_persist(
    float* buf0, float* buf1,
    const uint16_t* __restrict__ Whh0h, const uint16_t* __restrict__ Whh0l,
    const uint16_t* __restrict__ Wih1h, const uint16_t* __restrict__ Wih1l,
    const uint16_t* __restrict__ Whh1h, const uint16_t* __restrict__ Whh1l,
    const float* __restrict__ bhh0, const float* __restrict__ bih1,
    const float* __restrict__ bhh1,
    uint32_t* h0s, uint32_t* h1s,
    unsigned int* ctr, int T, int first)
{
  __shared__ float red[8*64*34];   // 68 KB: [wave][lane][32 regs pad->34]
  const int tid  = threadIdx.x;
  const int lane = tid & 63;
  const int w    = tid >> 6;                 // 0..7 = K-slice id
  const int lr   = lane & 15, kg = lane >> 4;
  const int wg   = blockIdx.x;
  const int group = wg >> 5;                 // 0,1,2
  const int sub  = wg & 31;
  const int wgRow = sub >> 4;                // 0..1  (rows 32*wgRow)
  const int wgN   = sub & 15;                // 0..15 (cols 64*wgN)

  const uint16_t* Whp = (group == 0) ? Whh0h : (group == 1) ? Wih1h : Whh1h;
  const uint16_t* Wlp = (group == 0) ? Whh0l : (group == 1) ? Wih1l : Whh1l;

  // preload weight fragments: 4 n-tiles x 4 k-steps, hi+lo (128 VGPR)
  short8 wh[4][4], wl[4][4];
#pragma unroll
  for (int nt = 0; nt < 4; ++nt){
    const int wr = wgN*64 + nt*16 + lr;
#pragma unroll
    for (int ks = 0; ks < 4; ++ks){
      const int k = w*128 + ks*32 + kg*8;
      wh[nt][ks] = *(const short8*)&Whp[(size_t)wr*HID + k];
      wl[nt][ks] = *(const short8*)&Wlp[(size_t)wr*HID + k];
    }
  }

  const int R = T + 2;
  for (int r = 0; r < R; ++r){
    const int t = r - group;
    if (t >= 0 && t < T){
      // select A (packed h) pointer for this round
      const uint32_t* Ap;
      if (group == 0)
        Ap = (t == 0) ? (first ? (const uint32_t*)0 : h0s)
                      : (const uint32_t*)buf0 + (size_t)(t-1)*(BAT*HID);
      else if (group == 1)
        Ap = (const uint32_t*)buf0 + (size_t)t*(BAT*HID);
      else
        Ap = (t == 0) ? (first ? (const uint32_t*)0 : h1s)
                      : (const uint32_t*)buf1 + (size_t)(t-1)*(BAT*HID);

      f32x4 acc[2][4];
#pragma unroll
      for (int mt = 0; mt < 2; ++mt)
#pragma unroll
        for (int nt = 0; nt < 4; ++nt) acc[mt][nt] = (f32x4){0.f,0.f,0.f,0.f};

      if (Ap){
#pragma unroll
        for (int mt = 0; mt < 2; ++mt){
          const int row = wgRow*32 + mt*16 + lr;
          const uint32_t* p = Ap + (size_t)row*HID + w*128 + kg*8;
#pragma unroll
          for (int ks = 0; ks < 4; ++ks){
            uint4 a0 = *(const uint4*)(p + ks*32);
            uint4 a1 = *(const uint4*)(p + ks*32 + 4);
            Frag8 fh, fl;
            unpack_pair(a0.x, a0.y, fh.u[0], fl.u[0]);
            unpack_pair(a0.z, a0.w, fh.u[1], fl.u[1]);
            unpack_pair(a1.x, a1.y, fh.u[2], fl.u[2]);
            unpack_pair(a1.z, a1.w, fh.u[3], fl.u[3]);
#pragma unroll
            for (int nt = 0; nt < 4; ++nt){
              acc[mt][nt] = __builtin_amdgcn_mfma_f32_16x16x32_bf16(fh.s, wh[nt][ks], acc[mt][nt], 0,0,0);
              acc[mt][nt] = __builtin_amdgcn_mfma_f32_16x16x32_bf16(fl.s, wh[nt][ks], acc[mt][nt], 0,0,0);
              acc[mt][nt] = __builtin_amdgcn_mfma_f32_16x16x32_bf16(fh.s, wl[nt][ks], acc[mt][nt], 0,0,0);
            }
          }
        }
      }
      // cross-wave K reduction through LDS
#pragma unroll
      for (int mt = 0; mt < 2; ++mt)
#pragma unroll
        for (int nt = 0; nt < 4; ++nt){
          const int base = (w*64 + lane)*34 + mt*16 + nt*4;
          *(float2*)&red[base]     = (float2){acc[mt][nt][0], acc[mt][nt][1]};
          *(float2*)&red[base + 2] = (float2){acc[mt][nt][2], acc[mt][nt][3]};
        }
      __syncthreads();
      const int mtr = w >> 2, ntr = w & 3;       // this wave reduces regs [w*4, w*4+4)
      const int reg = mtr*16 + ntr*4;
      f32x4 s = (f32x4){0.f,0.f,0.f,0.f};
#pragma unroll
      for (int ww = 0; ww < 8; ++ww){
        const int base = (ww*64 + lane)*34 + reg;
        float2 p0 = *(const float2*)&red[base];
        float2 p1 = *(const float2*)&red[base + 2];
        s[0] += p0.x; s[1] += p0.y; s[2] += p1.x; s[3] += p1.y;
      }
      // epilogue
      const int col = wgN*64 + ntr*16 + lr;
      if (group == 0){
        const float bv = bhh0[col];
#pragma unroll
        for (int q = 0; q < 4; ++q){
          const int row = wgRow*32 + mtr*16 + kg*4 + q;
          const size_t idx = (size_t)t*(BAT*HID) + (size_t)row*HID + col;
          float v = tanhf(s[q] + buf0[idx] + bv);
          uint32_t pk = pack_split(v);
          ((uint32_t*)buf0)[idx] = pk;
          if (t == T-1) h0s[(size_t)row*HID + col] = pk;
        }
      } else if (group == 1){
        const float bv = bih1[col] + bhh1[col];
#pragma unroll
        for (int q = 0; q < 4; ++q){
          const int row = wgRow*32 + mtr*16 + kg*4 + q;
          const size_t idx = (size_t)t*(BAT*HID) + (size_t)row*HID + col;
          buf1[idx] = s[q] + bv;
        }
      } else {
#pragma unroll
        for (int q = 0; q < 4; ++q){
          const int row = wgRow*32 + mtr*16 + kg*4 + q;
          const size_t idx = (size_t)t*(BAT*HID) + (size_t)row*HID + col;
          float v = tanhf(s[q] + buf1[idx]);
          uint32_t pk = pack_split(v);
          ((uint32_t*)buf1)[idx] = pk;
          if (t == T-1) h1s[(size_t)row*HID + col] = pk;
        }
      }
    }
    // ---- grid-wide barrier (device-scope monotonic counter) ----
    __syncthreads();
    if (tid == 0){
      __hip_atomic_fetch_add(ctr, 1u, __ATOMIC_ACQ_REL, __HIP_MEMORY_SCOPE_AGENT);
      const unsigned tgt = (unsigned)NWG_PERSIST * (unsigned)(r + 1);
      unsigned spins = 0;
      while (__hip_atomic_load(ctr, __ATOMIC_ACQUIRE, __HIP_MEMORY_SCOPE_AGENT) < tgt){
        __builtin_amdgcn_s_sleep(1);
        if (++spins > (1u << 20)) break;   // failsafe: no hang
      }
    }
    __syncthreads();
  }
}

// ---------- hidden output from carried states ----------
__global__ void extract_hidden(const uint32_t* __restrict__ h0s,
                               const uint32_t* __restrict__ h1s,
                               float* __restrict__ out){
  int i = blockIdx.x*256 + threadIdx.x;   // 0..131071
  uint32_t p = (i >> 16) ? h1s[i & 65535] : h0s[i & 65535];
  out[(size_t)SB*INF + i] = __uint_as_float(p & 0xFFFF0000u) + __uint_as_float(p << 16);
}

// ---------- host ----------
extern "C" void kernel_launch(void* const* d_in, const int* in_sizes, int n_in,
                              void* d_out, int out_size, void* d_ws, size_t ws_size,
                              hipStream_t stream)
{
  const float* x    = (const float*)d_in[0];
  const float* W_in = (const float*)d_in[1];
  const float* b_in = (const float*)d_in[2];
  const float* W_ih = (const float*)d_in[3];   // [2][H][H]
  const float* W_hh = (const float*)d_in[4];   // [2][H][H]
  const float* b_ih = (const float*)d_in[5];   // [2][H]
  const float* b_hh = (const float*)d_in[6];   // [2][H]
  const float* W_out= (const float*)d_in[7];   // [I][H]
  const float* b_out= (const float*)d_in[8];
  float* out = (float*)d_out;
  (void)in_sizes; (void)n_in; (void)out_size;

  // ---- choose chunk length T to fit ws_size ----
  const size_t fixedB = 16257024 + 4096;
  const size_t perT   = 589824;
  int T = 512;
  while (T > 2 && fixedB + (size_t)T*perT + 65536 > ws_size) T >>= 1;
  const int nchunk = SEQ / T;

  char* ws = (char*)d_ws;
  size_t off = 0;
  auto alloc = [&](size_t bytes)->void*{
    void* p = ws + off; off += (bytes + 255) & ~(size_t)255; return p;
  };
  float*    buf0   = (float*)   alloc((size_t)T*BAT*HID*4);  // pre0 -> packed h0 (chunk)
  float*    buf1   = (float*)   alloc((size_t)T*BAT*HID*4);  // pre1 -> packed h1 (chunk)
  uint32_t* xp     = (uint32_t*)alloc((size_t)T*BAT*INF*4);  // packed x (chunk)
  float*    WcombF = (float*)   alloc((size_t)HID*INF*4);
  uint16_t* Wc_hi  = (uint16_t*)alloc((size_t)HID*INF*2);
  uint16_t* Wc_lo  = (uint16_t*)alloc((size_t)HID*INF*2);
  uint16_t* Wih1_hi= (uint16_t*)alloc((size_t)HID*HID*2);
  uint16_t* Wih1_lo= (uint16_t*)alloc((size_t)HID*HID*2);
  uint16_t* Whh0_hi= (uint16_t*)alloc((size_t)HID*HID*2);
  uint16_t* Whh0_lo= (uint16_t*)alloc((size_t)HID*HID*2);
  uint16_t* Whh1_hi= (uint16_t*)alloc((size_t)HID*HID*2);
  uint16_t* Whh1_lo= (uint16_t*)alloc((size_t)HID*HID*2);
  uint16_t* Wout_hi= (uint16_t*)alloc((size_t)INF*HID*2);
  uint16_t* Wout_lo= (uint16_t*)alloc((size_t)INF*HID*2);
  float*    bcomb  = (float*)   alloc((size_t)HID*4);
  uint32_t* h0s    = (uint32_t*)alloc((size_t)BAT*HID*4);
  uint32_t* h1s    = (uint32_t*)alloc((size_t)BAT*HID*4);
  unsigned int* ctr= (unsigned int*)alloc(256);

  // ---- prep ----
  wcomb_kernel<<<HID/16, 256, 0, stream>>>(W_ih, W_in, WcombF);
  bcomb_kernel<<<HID, 256, 0, stream>>>(W_ih, b_in, b_ih, bcomb);
  split_w<<<(HID*INF+255)/256, 256, 0, stream>>>(WcombF, Wc_hi, Wc_lo, HID*INF);
  split_w<<<(HID*HID+255)/256, 256, 0, stream>>>(W_ih + (size_t)HID*HID, Wih1_hi, Wih1_lo, HID*HID);
  split_w<<<(HID*HID+255)/256, 256, 0, stream>>>(W_hh, Whh0_hi, Whh0_lo, HID*HID);
  split_w<<<(HID*HID+255)/256, 256, 0, stream>>>(W_hh + (size_t)HID*HID, Whh1_hi, Whh1_lo, HID*HID);
  split_w<<<(INF*HID+255)/256, 256, 0, stream>>>(W_out, Wout_hi, Wout_lo, INF*HID);

  // ---- chunked pipeline ----
  for (int c = 0; c < nchunk; ++c){
    const float* xc = x + (size_t)c*T*BAT*INF;
    pack_x<<<T*BAT*INF/256, 256, 0, stream>>>(xc, xp, T*BAT*INF);
    // pre0 chunk = xp @ Wcomb^T + bcomb
    gemm_split<<<dim3(T*64/128, HID/128), 256, 0, stream>>>(xp, Wc_hi, Wc_lo, bcomb, buf0, HID, INF);
    // wavefront scan over the chunk (both layers + pre1 fused)
    hipMemsetAsync(ctr, 0, sizeof(unsigned int), stream);
    rnn_persist<<<NWG_PERSIST, 512, 0, stream>>>(
        buf0, buf1, Whh0_hi, Whh0_lo, Wih1_hi, Wih1_lo, Whh1_hi, Whh1_lo,
        b_hh, b_ih + HID, b_hh + HID, h0s, h1s, ctr, T, (c == 0) ? 1 : 0);
    // out chunk = h1chunk @ Wout^T + b_out
    gemm_split<<<dim3(T*64/128, INF/128), 256, 0, stream>>>((const uint32_t*)buf1, Wout_hi, Wout_lo,
                                                            b_out, out + (size_t)c*T*BAT*INF, INF, HID);
  }
  extract_hidden<<<(2*BAT*HID)/256, 256, 0, stream>>>(h0s, h1s, out);
}